// Round 1
// baseline (309.301 us; speedup 1.0000x reference)
//
#include <hip/hip_runtime.h>
#include <hip/hip_bf16.h>

typedef __bf16 bf16;
typedef bf16 bf16x8 __attribute__((ext_vector_type(8)));
typedef float f32x4 __attribute__((ext_vector_type(4)));

constexpr int B = 4, C = 512, L = 2048, H = 8, DH = 64;
constexpr int BL = B * L;        // 8192
constexpr int N_QKV = 3 * C;     // 1536
constexpr float SCALE = 0.125f;  // DH^-0.5
constexpr float EPS = 1e-5f;

// ---- workspace layout (bytes) ----
constexpr size_t SZ = (size_t)BL * C;                 // 4,194,304 elems
constexpr size_t OFF_HN    = 0;                       // SZ bf16
constexpr size_t OFF_WQKV  = OFF_HN    + SZ * 2;      // N_QKV*C bf16
constexpr size_t OFF_WPROJ = OFF_WQKV  + (size_t)N_QKV * C * 2;
constexpr size_t OFF_Q     = OFF_WPROJ + (size_t)C * C * 2;
constexpr size_t OFF_K     = OFF_Q     + SZ * 2;
constexpr size_t OFF_V     = OFF_K     + SZ * 2;
constexpr size_t OFF_O     = OFF_V     + SZ * 2;
constexpr size_t OFF_STATS = OFF_O     + SZ * 2;      // BL*2 fp32

__device__ __forceinline__ bf16x8 ld8(const bf16* p) {
  return *(const bf16x8*)p;
}

// ---------------- weight conversion ----------------
__global__ __launch_bounds__(256) void k_convert_w(const float* __restrict__ wqkv,
                                                   const float* __restrict__ wproj,
                                                   bf16* __restrict__ wqkv_b,
                                                   bf16* __restrict__ wproj_b) {
  int i = blockIdx.x * 256 + threadIdx.x;
  if (i < N_QKV * C) wqkv_b[i] = (bf16)wqkv[i];
  if (i < C * C)     wproj_b[i] = (bf16)wproj[i];
}

// ---------------- LayerNorm stats ----------------
__global__ __launch_bounds__(1024) void k_ln_stats(const float* __restrict__ x,
                                                   float* __restrict__ stats) {
  // grid: B * (L/64) = 128 blocks, 1024 threads
  int blk = blockIdx.x;
  int b = blk >> 5;
  int l0 = (blk & 31) << 6;
  int lane = threadIdx.x & 63;
  int w = threadIdx.x >> 6;  // 0..15
  const float* xp = x + ((size_t)b * C) * L + l0 + lane;
  float s = 0.f, ss = 0.f;
#pragma unroll
  for (int r = 0; r < 32; ++r) {
    float v = xp[(size_t)(w + r * 16) * L];
    s += v; ss += v * v;
  }
  __shared__ float sh_s[16][64];
  __shared__ float sh_q[16][64];
  sh_s[w][lane] = s; sh_q[w][lane] = ss;
  __syncthreads();
  if (threadIdx.x < 64) {
    float ts = 0.f, tq = 0.f;
#pragma unroll
    for (int i = 0; i < 16; ++i) { ts += sh_s[i][lane]; tq += sh_q[i][lane]; }
    float mu = ts * (1.0f / C);
    float var = tq * (1.0f / C) - mu * mu;
    float rstd = rsqrtf(var + EPS);
    int idx = b * L + l0 + lane;
    stats[idx * 2]     = mu;
    stats[idx * 2 + 1] = rstd;
  }
}

// ---------------- LayerNorm normalize + transpose to [BL, C] bf16 ----------------
__global__ __launch_bounds__(256) void k_ln_norm(const float* __restrict__ x,
                                                 const float* __restrict__ stats,
                                                 const float* __restrict__ gamma,
                                                 const float* __restrict__ beta,
                                                 bf16* __restrict__ hn) {
  // grid: b(4) * lt(32) * ct(8) = 1024 blocks
  int blk = blockIdx.x;
  int ct = blk & 7;  blk >>= 3;
  int lt = blk & 31; int b = blk >> 5;
  int c0 = ct << 6, l0 = lt << 6;
  int lane = threadIdx.x & 63, w = threadIdx.x >> 6;
  __shared__ float tile[64][65];
  const float* xp = x + (size_t)(b * C + c0) * L + l0;
#pragma unroll
  for (int r = 0; r < 16; ++r) {
    int c = w * 16 + r;
    tile[c][lane] = xp[(size_t)c * L + lane];
  }
  __syncthreads();
  float g = gamma[c0 + lane], be = beta[c0 + lane];
  bf16* hp = hn + (size_t)(b * L + l0) * C + c0 + lane;
#pragma unroll
  for (int r = 0; r < 16; ++r) {
    int ll = w * 16 + r;
    float mu   = stats[(b * L + l0 + ll) * 2];
    float rstd = stats[(b * L + l0 + ll) * 2 + 1];
    float v = (tile[lane][ll] - mu) * rstd * g + be;
    hp[(size_t)ll * C] = (bf16)v;
  }
}

// ---------------- QKV GEMM: [8192,512] x [1536,512]^T -> q/k/v [B,H,L,DH] bf16 ----------------
__global__ __launch_bounds__(256) void k_gemm_qkv(const bf16* __restrict__ hn,
                                                  const bf16* __restrict__ wq,
                                                  const float* __restrict__ bq,
                                                  bf16* __restrict__ qb,
                                                  bf16* __restrict__ kb,
                                                  bf16* __restrict__ vb) {
  int mt = blockIdx.x, nt = blockIdx.y;  // 128 x 24
  int m0 = mt << 6, n0 = nt << 6;
  int t = threadIdx.x;
  int lane = t & 63, w = t >> 6;
  int q4 = lane >> 4, c16 = lane & 15;
  __shared__ __align__(16) bf16 As[64][72];
  __shared__ __align__(16) bf16 Bs[64][72];
  f32x4 acc[4];
#pragma unroll
  for (int nb = 0; nb < 4; ++nb) acc[nb] = (f32x4){0.f, 0.f, 0.f, 0.f};

  for (int k0 = 0; k0 < C; k0 += 64) {
    __syncthreads();
#pragma unroll
    for (int p = 0; p < 2; ++p) {
      int idx = p * 256 + t;
      int row = idx >> 3, ch = idx & 7;
      *(bf16x8*)&As[row][ch * 8] = *(const bf16x8*)&hn[(size_t)(m0 + row) * C + k0 + ch * 8];
      *(bf16x8*)&Bs[row][ch * 8] = *(const bf16x8*)&wq[(size_t)(n0 + row) * C + k0 + ch * 8];
    }
    __syncthreads();
#pragma unroll
    for (int kk = 0; kk < 64; kk += 32) {
      bf16x8 a = ld8(&As[w * 16 + c16][kk + q4 * 8]);
#pragma unroll
      for (int nb = 0; nb < 4; ++nb) {
        bf16x8 bfr = ld8(&Bs[nb * 16 + c16][kk + q4 * 8]);
        acc[nb] = __builtin_amdgcn_mfma_f32_16x16x32_bf16(a, bfr, acc[nb], 0, 0, 0);
      }
    }
  }
  __syncthreads();
  // epilogue: bias, to LDS (reuse As), then coalesced split store
  float bias[4];
#pragma unroll
  for (int nb = 0; nb < 4; ++nb) bias[nb] = bq[n0 + nb * 16 + c16];
#pragma unroll
  for (int nb = 0; nb < 4; ++nb)
#pragma unroll
    for (int r = 0; r < 4; ++r)
      As[w * 16 + q4 * 4 + r][nb * 16 + c16] = (bf16)(acc[nb][r] + bias[nb]);
  __syncthreads();
  int i = nt >> 3, h = nt & 7;
  bf16* dst0 = (i == 0) ? qb : (i == 1) ? kb : vb;
  int b = m0 >> 11;        // m0 / L
  int l0 = m0 & (L - 1);
  int row = t >> 2, seg = t & 3;
  const bf16* src = &As[row][seg * 16];
  bf16* dst = dst0 + (size_t)((b * H + h) * L + l0 + row) * DH + seg * 16;
  *(uint4*)dst       = *(const uint4*)src;
  *(uint4*)(dst + 8) = *(const uint4*)(src + 8);
}

// ---------------- flash attention: 64 q-rows per block ----------------
__global__ __launch_bounds__(256) void k_attn(const bf16* __restrict__ qb,
                                              const bf16* __restrict__ kb,
                                              const bf16* __restrict__ vb,
                                              bf16* __restrict__ ob) {
  int blk = blockIdx.x;              // ((b*H + h) * 32 + qt)
  int qt = blk & 31; int bh = blk >> 5;
  int t = threadIdx.x, lane = t & 63, w = t >> 6;
  int q4 = lane >> 4, c16 = lane & 15;
  __shared__ __align__(16) bf16 Qs[64][72];
  __shared__ __align__(16) bf16 Ks[64][72];
  __shared__ __align__(16) bf16 Vts[64][72];
  __shared__ __align__(16) bf16 Ps[4][16][72];
  const bf16* qptr = qb + ((size_t)bh * L + (qt << 6)) * DH;
  const bf16* kptr = kb + (size_t)bh * L * DH;
  const bf16* vptr = vb + (size_t)bh * L * DH;
#pragma unroll
  for (int p = 0; p < 2; ++p) {
    int idx = p * 256 + t;
    int row = idx >> 3, ch = idx & 7;
    *(bf16x8*)&Qs[row][ch * 8] = *(const bf16x8*)&qptr[(size_t)row * DH + ch * 8];
  }
  f32x4 o_acc[4];
#pragma unroll
  for (int nb = 0; nb < 4; ++nb) o_acc[nb] = (f32x4){0.f, 0.f, 0.f, 0.f};
  float m_i[4], l_i[4];
#pragma unroll
  for (int r = 0; r < 4; ++r) { m_i[r] = -1e30f; l_i[r] = 0.f; }

  for (int j0 = 0; j0 < L; j0 += 64) {
    __syncthreads();
#pragma unroll
    for (int p = 0; p < 2; ++p) {
      int idx = p * 256 + t;
      int row = idx >> 3, ch = idx & 7;
      *(bf16x8*)&Ks[row][ch * 8] = *(const bf16x8*)&kptr[(size_t)(j0 + row) * DH + ch * 8];
      bf16x8 vv = *(const bf16x8*)&vptr[(size_t)(j0 + row) * DH + ch * 8];
#pragma unroll
      for (int e = 0; e < 8; ++e) Vts[ch * 8 + e][row] = vv[e];
    }
    __syncthreads();
    // S = Q K^T
    f32x4 s[4];
#pragma unroll
    for (int nb = 0; nb < 4; ++nb) s[nb] = (f32x4){0.f, 0.f, 0.f, 0.f};
#pragma unroll
    for (int kk = 0; kk < 64; kk += 32) {
      bf16x8 a = ld8(&Qs[w * 16 + c16][kk + q4 * 8]);
#pragma unroll
      for (int nb = 0; nb < 4; ++nb) {
        bf16x8 bfr = ld8(&Ks[nb * 16 + c16][kk + q4 * 8]);
        s[nb] = __builtin_amdgcn_mfma_f32_16x16x32_bf16(a, bfr, s[nb], 0, 0, 0);
      }
    }
    // online softmax per owned row (rows q4*4+r, 16 lanes/row share via shfl)
#pragma unroll
    for (int r = 0; r < 4; ++r) {
      float mx = -1e30f;
#pragma unroll
      for (int nb = 0; nb < 4; ++nb) { s[nb][r] *= SCALE; mx = fmaxf(mx, s[nb][r]); }
#pragma unroll
      for (int msk = 1; msk < 16; msk <<= 1) mx = fmaxf(mx, __shfl_xor(mx, msk, 64));
      float mn = fmaxf(m_i[r], mx);
      float alpha = __expf(m_i[r] - mn);
      float rs = 0.f;
#pragma unroll
      for (int nb = 0; nb < 4; ++nb) {
        float p_ = __expf(s[nb][r] - mn);
        s[nb][r] = p_;
        rs += p_;
      }
#pragma unroll
      for (int msk = 1; msk < 16; msk <<= 1) rs += __shfl_xor(rs, msk, 64);
      l_i[r] = l_i[r] * alpha + rs;
      m_i[r] = mn;
#pragma unroll
      for (int nb = 0; nb < 4; ++nb) o_acc[nb][r] *= alpha;
    }
    // P: C-layout -> A-layout via wave-private LDS
#pragma unroll
    for (int nb = 0; nb < 4; ++nb)
#pragma unroll
      for (int r = 0; r < 4; ++r)
        Ps[w][q4 * 4 + r][nb * 16 + c16] = (bf16)s[nb][r];
    // O += P V
#pragma unroll
    for (int kk = 0; kk < 64; kk += 32) {
      bf16x8 a = ld8(&Ps[w][c16][kk + q4 * 8]);
#pragma unroll
      for (int nb = 0; nb < 4; ++nb) {
        bf16x8 bfr = ld8(&Vts[nb * 16 + c16][kk + q4 * 8]);
        o_acc[nb] = __builtin_amdgcn_mfma_f32_16x16x32_bf16(a, bfr, o_acc[nb], 0, 0, 0);
      }
    }
  }
  // epilogue: divide by l, store o row-major [BL][C]
  int b = bh >> 3, h = bh & 7;
  int q0 = (qt << 6) + w * 16;
#pragma unroll
  for (int r = 0; r < 4; ++r) {
    float inv = 1.0f / l_i[r];
    int qrow = q0 + q4 * 4 + r;
    bf16* op = ob + (size_t)(b * L + qrow) * C + h * DH;
#pragma unroll
    for (int nb = 0; nb < 4; ++nb)
      op[nb * 16 + c16] = (bf16)(o_acc[nb][r] * inv);
  }
}

// ---------------- proj GEMM + bias + residual, output [B,C,L] fp32 ----------------
__global__ __launch_bounds__(256) void k_gemm_proj(const bf16* __restrict__ ob,
                                                   const bf16* __restrict__ wp,
                                                   const float* __restrict__ bp,
                                                   const float* __restrict__ x,
                                                   float* __restrict__ out) {
  int mt = blockIdx.x, nt = blockIdx.y;  // 128 x 8
  int m0 = mt << 6, n0 = nt << 6;
  int t = threadIdx.x;
  int lane = t & 63, w = t >> 6;
  int q4 = lane >> 4, c16 = lane & 15;
  __shared__ __align__(16) bf16 As[64][72];
  __shared__ __align__(16) bf16 Bs[64][72];
  __shared__ float Ot[64][65];
  f32x4 acc[4];
#pragma unroll
  for (int nb = 0; nb < 4; ++nb) acc[nb] = (f32x4){0.f, 0.f, 0.f, 0.f};

  for (int k0 = 0; k0 < C; k0 += 64) {
    __syncthreads();
#pragma unroll
    for (int p = 0; p < 2; ++p) {
      int idx = p * 256 + t;
      int row = idx >> 3, ch = idx & 7;
      *(bf16x8*)&As[row][ch * 8] = *(const bf16x8*)&ob[(size_t)(m0 + row) * C + k0 + ch * 8];
      *(bf16x8*)&Bs[row][ch * 8] = *(const bf16x8*)&wp[(size_t)(n0 + row) * C + k0 + ch * 8];
    }
    __syncthreads();
#pragma unroll
    for (int kk = 0; kk < 64; kk += 32) {
      bf16x8 a = ld8(&As[w * 16 + c16][kk + q4 * 8]);
#pragma unroll
      for (int nb = 0; nb < 4; ++nb) {
        bf16x8 bfr = ld8(&Bs[nb * 16 + c16][kk + q4 * 8]);
        acc[nb] = __builtin_amdgcn_mfma_f32_16x16x32_bf16(a, bfr, acc[nb], 0, 0, 0);
      }
    }
  }
  __syncthreads();
#pragma unroll
  for (int nb = 0; nb < 4; ++nb)
#pragma unroll
    for (int r = 0; r < 4; ++r)
      Ot[w * 16 + q4 * 4 + r][nb * 16 + c16] = acc[nb][r];
  __syncthreads();
  int b = m0 >> 11, l0 = m0 & (L - 1);
#pragma unroll
  for (int r = 0; r < 16; ++r) {
    int cl = w * 16 + r;
    int c = n0 + cl;
    size_t idx = (size_t)(b * C + c) * L + l0 + lane;
    out[idx] = Ot[lane][cl] + bp[c] + x[idx];
  }
}

extern "C" void kernel_launch(void* const* d_in, const int* in_sizes, int n_in,
                              void* d_out, int out_size, void* d_ws, size_t ws_size,
                              hipStream_t stream) {
  const float* x     = (const float*)d_in[0];
  const float* gamma = (const float*)d_in[1];
  const float* beta  = (const float*)d_in[2];
  const float* wqkv  = (const float*)d_in[3];
  const float* bqkv  = (const float*)d_in[4];
  const float* wproj = (const float*)d_in[5];
  const float* bproj = (const float*)d_in[6];
  float* out = (float*)d_out;
  char* ws = (char*)d_ws;
  bf16* hn  = (bf16*)(ws + OFF_HN);
  bf16* wqb = (bf16*)(ws + OFF_WQKV);
  bf16* wpb = (bf16*)(ws + OFF_WPROJ);
  bf16* qb  = (bf16*)(ws + OFF_Q);
  bf16* kb  = (bf16*)(ws + OFF_K);
  bf16* vb  = (bf16*)(ws + OFF_V);
  bf16* ob  = (bf16*)(ws + OFF_O);
  float* stats = (float*)(ws + OFF_STATS);

  hipLaunchKernelGGL(k_convert_w, dim3((N_QKV * C + 255) / 256), dim3(256), 0, stream,
                     wqkv, wproj, wqb, wpb);
  hipLaunchKernelGGL(k_ln_stats, dim3(B * (L / 64)), dim3(1024), 0, stream, x, stats);
  hipLaunchKernelGGL(k_ln_norm, dim3(B * (L / 64) * (C / 64)), dim3(256), 0, stream,
                     x, stats, gamma, beta, hn);
  hipLaunchKernelGGL(k_gemm_qkv, dim3(BL / 64, N_QKV / 64), dim3(256), 0, stream,
                     hn, wqb, bqkv, qb, kb, vb);
  hipLaunchKernelGGL(k_attn, dim3(B * H * (L / 64)), dim3(256), 0, stream, qb, kb, vb, ob);
  hipLaunchKernelGGL(k_gemm_proj, dim3(BL / 64, C / 64), dim3(256), 0, stream,
                     ob, wpb, bproj, x, out);
}

// Round 2
// 248.487 us; speedup vs baseline: 1.2447x; 1.2447x over previous
//
#include <hip/hip_runtime.h>
#include <hip/hip_bf16.h>

typedef __bf16 bf16;
typedef bf16 bf16x8 __attribute__((ext_vector_type(8)));
typedef float f32x4 __attribute__((ext_vector_type(4)));

constexpr int B = 4, C = 512, L = 2048, H = 8, DH = 64;
constexpr int BL = B * L;        // 8192
constexpr int N_QKV = 3 * C;     // 1536
constexpr float SCALE = 0.125f;  // DH^-0.5 (exact power of 2)
constexpr float EPS = 1e-5f;

// ---- workspace layout (bytes) ----
constexpr size_t SZ = (size_t)BL * C;                 // 4,194,304 elems
constexpr size_t OFF_HN    = 0;                       // SZ bf16
constexpr size_t OFF_WQKV  = OFF_HN    + SZ * 2;      // N_QKV*C bf16
constexpr size_t OFF_WPROJ = OFF_WQKV  + (size_t)N_QKV * C * 2;
constexpr size_t OFF_Q     = OFF_WPROJ + (size_t)C * C * 2;
constexpr size_t OFF_K     = OFF_Q     + SZ * 2;
constexpr size_t OFF_V     = OFF_K     + SZ * 2;      // V stored TRANSPOSED [B,H,DH,L]
constexpr size_t OFF_O     = OFF_V     + SZ * 2;
constexpr size_t OFF_STATS = OFF_O     + SZ * 2;      // BL*2 fp32

__device__ __forceinline__ bf16x8 ld8(const bf16* p) {
  return *(const bf16x8*)p;
}

// ---------------- weight conversion ----------------
__global__ __launch_bounds__(256) void k_convert_w(const float* __restrict__ wqkv,
                                                   const float* __restrict__ wproj,
                                                   bf16* __restrict__ wqkv_b,
                                                   bf16* __restrict__ wproj_b) {
  int i = blockIdx.x * 256 + threadIdx.x;
  if (i < N_QKV * C) wqkv_b[i] = (bf16)wqkv[i];
  if (i < C * C)     wproj_b[i] = (bf16)wproj[i];
}

// ---------------- LayerNorm stats ----------------
__global__ __launch_bounds__(1024) void k_ln_stats(const float* __restrict__ x,
                                                   float* __restrict__ stats) {
  // grid: B * (L/64) = 128 blocks, 1024 threads
  int blk = blockIdx.x;
  int b = blk >> 5;
  int l0 = (blk & 31) << 6;
  int lane = threadIdx.x & 63;
  int w = threadIdx.x >> 6;  // 0..15
  const float* xp = x + ((size_t)b * C) * L + l0 + lane;
  float s = 0.f, ss = 0.f;
#pragma unroll
  for (int r = 0; r < 32; ++r) {
    float v = xp[(size_t)(w + r * 16) * L];
    s += v; ss += v * v;
  }
  __shared__ float sh_s[16][64];
  __shared__ float sh_q[16][64];
  sh_s[w][lane] = s; sh_q[w][lane] = ss;
  __syncthreads();
  if (threadIdx.x < 64) {
    float ts = 0.f, tq = 0.f;
#pragma unroll
    for (int i = 0; i < 16; ++i) { ts += sh_s[i][lane]; tq += sh_q[i][lane]; }
    float mu = ts * (1.0f / C);
    float var = tq * (1.0f / C) - mu * mu;
    float rstd = rsqrtf(var + EPS);
    int idx = b * L + l0 + lane;
    stats[idx * 2]     = mu;
    stats[idx * 2 + 1] = rstd;
  }
}

// ---------------- LayerNorm normalize + transpose to [BL, C] bf16 ----------------
__global__ __launch_bounds__(256) void k_ln_norm(const float* __restrict__ x,
                                                 const float* __restrict__ stats,
                                                 const float* __restrict__ gamma,
                                                 const float* __restrict__ beta,
                                                 bf16* __restrict__ hn) {
  // grid: b(4) * lt(32) * ct(8) = 1024 blocks
  int blk = blockIdx.x;
  int ct = blk & 7;  blk >>= 3;
  int lt = blk & 31; int b = blk >> 5;
  int c0 = ct << 6, l0 = lt << 6;
  int lane = threadIdx.x & 63, w = threadIdx.x >> 6;
  __shared__ float tile[64][65];
  const float* xp = x + (size_t)(b * C + c0) * L + l0;
#pragma unroll
  for (int r = 0; r < 16; ++r) {
    int c = w * 16 + r;
    tile[c][lane] = xp[(size_t)c * L + lane];
  }
  __syncthreads();
  float g = gamma[c0 + lane], be = beta[c0 + lane];
  bf16* hp = hn + (size_t)(b * L + l0) * C + c0 + lane;
#pragma unroll
  for (int r = 0; r < 16; ++r) {
    int ll = w * 16 + r;
    float mu   = stats[(b * L + l0 + ll) * 2];
    float rstd = stats[(b * L + l0 + ll) * 2 + 1];
    float v = (tile[lane][ll] - mu) * rstd * g + be;
    hp[(size_t)ll * C] = (bf16)v;
  }
}

// ---------------- QKV GEMM: [8192,512] x [1536,512]^T -> q(scaled)/k [B,H,L,DH], v^T [B,H,DH,L] ----------------
__global__ __launch_bounds__(256) void k_gemm_qkv(const bf16* __restrict__ hn,
                                                  const bf16* __restrict__ wq,
                                                  const float* __restrict__ bq,
                                                  bf16* __restrict__ qb,
                                                  bf16* __restrict__ kb,
                                                  bf16* __restrict__ vb) {
  int mt = blockIdx.x, nt = blockIdx.y;  // 128 x 24
  int m0 = mt << 6, n0 = nt << 6;
  int t = threadIdx.x;
  int lane = t & 63, w = t >> 6;
  int q4 = lane >> 4, c16 = lane & 15;
  __shared__ __align__(16) bf16 As[64][72];
  __shared__ __align__(16) bf16 Bs[64][72];
  f32x4 acc[4];
#pragma unroll
  for (int nb = 0; nb < 4; ++nb) acc[nb] = (f32x4){0.f, 0.f, 0.f, 0.f};

  for (int k0 = 0; k0 < C; k0 += 64) {
    __syncthreads();
#pragma unroll
    for (int p = 0; p < 2; ++p) {
      int idx = p * 256 + t;
      int row = idx >> 3, ch = idx & 7;
      *(bf16x8*)&As[row][ch * 8] = *(const bf16x8*)&hn[(size_t)(m0 + row) * C + k0 + ch * 8];
      *(bf16x8*)&Bs[row][ch * 8] = *(const bf16x8*)&wq[(size_t)(n0 + row) * C + k0 + ch * 8];
    }
    __syncthreads();
#pragma unroll
    for (int kk = 0; kk < 64; kk += 32) {
      bf16x8 a = ld8(&As[w * 16 + c16][kk + q4 * 8]);
#pragma unroll
      for (int nb = 0; nb < 4; ++nb) {
        bf16x8 bfr = ld8(&Bs[nb * 16 + c16][kk + q4 * 8]);
        acc[nb] = __builtin_amdgcn_mfma_f32_16x16x32_bf16(a, bfr, acc[nb], 0, 0, 0);
      }
    }
  }
  __syncthreads();
  int i = nt >> 3, h = nt & 7;
  int b = m0 >> 11;        // m0 / L
  int l0 = m0 & (L - 1);
  float bias[4];
#pragma unroll
  for (int nb = 0; nb < 4; ++nb) bias[nb] = bq[n0 + nb * 16 + c16];

  if (i == 2) {
    // V: write TRANSPOSED tile into As[d][l], store as [B,H,DH,L]
#pragma unroll
    for (int nb = 0; nb < 4; ++nb)
#pragma unroll
      for (int r = 0; r < 4; ++r)
        As[nb * 16 + c16][w * 16 + q4 * 4 + r] = (bf16)(acc[nb][r] + bias[nb]);
    __syncthreads();
    int d = t >> 2, seg = t & 3;
    const bf16* src = &As[d][seg * 16];
    bf16* dst = vb + (size_t)((b * H + h) * DH + d) * L + l0 + seg * 16;
    *(uint4*)dst       = *(const uint4*)src;
    *(uint4*)(dst + 8) = *(const uint4*)(src + 8);
  } else {
    // Q (pre-scaled by SCALE) or K: row-major [B,H,L,DH]
    float sc = (i == 0) ? SCALE : 1.0f;
#pragma unroll
    for (int nb = 0; nb < 4; ++nb)
#pragma unroll
      for (int r = 0; r < 4; ++r)
        As[w * 16 + q4 * 4 + r][nb * 16 + c16] = (bf16)((acc[nb][r] + bias[nb]) * sc);
    __syncthreads();
    bf16* dst0 = (i == 0) ? qb : kb;
    int row = t >> 2, seg = t & 3;
    const bf16* src = &As[row][seg * 16];
    bf16* dst = dst0 + (size_t)((b * H + h) * L + l0 + row) * DH + seg * 16;
    *(uint4*)dst       = *(const uint4*)src;
    *(uint4*)(dst + 8) = *(const uint4*)(src + 8);
  }
}

// ---------------- flash attention: 128 q-rows per block, 32 per wave ----------------
__global__ __launch_bounds__(256) void k_attn(const bf16* __restrict__ qb,
                                              const bf16* __restrict__ kb,
                                              const bf16* __restrict__ vt,
                                              bf16* __restrict__ ob) {
  int blk = blockIdx.x;              // bh*16 + qt
  int qt = blk & 15; int bh = blk >> 4;
  int t = threadIdx.x, lane = t & 63, w = t >> 6;
  int q4 = lane >> 4, c16 = lane & 15;
  __shared__ __align__(16) bf16 Qs[128][72];
  __shared__ __align__(16) bf16 Ks[64][72];
  __shared__ __align__(16) bf16 Vts[64][72];   // [d][j]
  __shared__ __align__(16) bf16 Ps[4][16][72]; // per-wave P round-trip
  const bf16* qptr  = qb + ((size_t)bh * L + qt * 128) * DH;
  const bf16* kptr  = kb + (size_t)bh * L * DH;
  const bf16* vtptr = vt + (size_t)bh * DH * L;
#pragma unroll
  for (int p = 0; p < 4; ++p) {
    int idx = p * 256 + t;
    int row = idx >> 3, ch = idx & 7;
    *(bf16x8*)&Qs[row][ch * 8] = *(const bf16x8*)&qptr[(size_t)row * DH + ch * 8];
  }
  f32x4 o_acc[2][4];
  float m_i[2][4], l_i[2][4];
#pragma unroll
  for (int mb = 0; mb < 2; ++mb)
#pragma unroll
    for (int nb = 0; nb < 4; ++nb) o_acc[mb][nb] = (f32x4){0.f, 0.f, 0.f, 0.f};
#pragma unroll
  for (int mb = 0; mb < 2; ++mb)
#pragma unroll
    for (int r = 0; r < 4; ++r) { m_i[mb][r] = -1e30f; l_i[mb][r] = 0.f; }

  for (int j0 = 0; j0 < L; j0 += 64) {
    __syncthreads();
#pragma unroll
    for (int p = 0; p < 2; ++p) {
      int idx = p * 256 + t;
      int row = idx >> 3, ch = idx & 7;
      *(bf16x8*)&Ks[row][ch * 8]  = *(const bf16x8*)&kptr[(size_t)(j0 + row) * DH + ch * 8];
      *(bf16x8*)&Vts[row][ch * 8] = *(const bf16x8*)&vtptr[(size_t)row * L + j0 + ch * 8];
    }
    __syncthreads();
    // S = Q K^T  (Q pre-scaled by SCALE)
    f32x4 s[2][4];
#pragma unroll
    for (int mb = 0; mb < 2; ++mb)
#pragma unroll
      for (int nb = 0; nb < 4; ++nb) s[mb][nb] = (f32x4){0.f, 0.f, 0.f, 0.f};
#pragma unroll
    for (int kk2 = 0; kk2 < 2; ++kk2) {
      bf16x8 kf[4];
#pragma unroll
      for (int nb = 0; nb < 4; ++nb) kf[nb] = ld8(&Ks[nb * 16 + c16][kk2 * 32 + q4 * 8]);
#pragma unroll
      for (int mb = 0; mb < 2; ++mb) {
        bf16x8 a = ld8(&Qs[w * 32 + mb * 16 + c16][kk2 * 32 + q4 * 8]);
#pragma unroll
        for (int nb = 0; nb < 4; ++nb)
          s[mb][nb] = __builtin_amdgcn_mfma_f32_16x16x32_bf16(a, kf[nb], s[mb][nb], 0, 0, 0);
      }
    }
    // online softmax per owned row (16 lanes/row share via shfl over the quad group)
#pragma unroll
    for (int mb = 0; mb < 2; ++mb)
#pragma unroll
      for (int r = 0; r < 4; ++r) {
        float mx = -1e30f;
#pragma unroll
        for (int nb = 0; nb < 4; ++nb) mx = fmaxf(mx, s[mb][nb][r]);
#pragma unroll
        for (int msk = 1; msk < 16; msk <<= 1) mx = fmaxf(mx, __shfl_xor(mx, msk, 64));
        float mn = fmaxf(m_i[mb][r], mx);
        float alpha = __expf(m_i[mb][r] - mn);
        float rs = 0.f;
#pragma unroll
        for (int nb = 0; nb < 4; ++nb) {
          float p_ = __expf(s[mb][nb][r] - mn);
          s[mb][nb][r] = p_;
          rs += p_;
        }
#pragma unroll
        for (int msk = 1; msk < 16; msk <<= 1) rs += __shfl_xor(rs, msk, 64);
        l_i[mb][r] = l_i[mb][r] * alpha + rs;
        m_i[mb][r] = mn;
#pragma unroll
        for (int nb = 0; nb < 4; ++nb) o_acc[mb][nb][r] *= alpha;
      }
    // V fragments (register-hoisted, reused across both m-blocks)
    bf16x8 vf[2][4];
#pragma unroll
    for (int kk2 = 0; kk2 < 2; ++kk2)
#pragma unroll
      for (int nb = 0; nb < 4; ++nb)
        vf[kk2][nb] = ld8(&Vts[nb * 16 + c16][kk2 * 32 + q4 * 8]);
    // O += P V  (P via wave-private LDS round-trip, one m-block at a time)
#pragma unroll
    for (int mb = 0; mb < 2; ++mb) {
#pragma unroll
      for (int nb = 0; nb < 4; ++nb)
#pragma unroll
        for (int r = 0; r < 4; ++r)
          Ps[w][q4 * 4 + r][nb * 16 + c16] = (bf16)s[mb][nb][r];
#pragma unroll
      for (int kk2 = 0; kk2 < 2; ++kk2) {
        bf16x8 a = ld8(&Ps[w][c16][kk2 * 32 + q4 * 8]);
#pragma unroll
        for (int nb = 0; nb < 4; ++nb)
          o_acc[mb][nb] = __builtin_amdgcn_mfma_f32_16x16x32_bf16(a, vf[kk2][nb], o_acc[mb][nb], 0, 0, 0);
      }
    }
  }
  // epilogue: divide by l, store o row-major [BL][C]
  int b = bh >> 3, h = bh & 7;
#pragma unroll
  for (int mb = 0; mb < 2; ++mb)
#pragma unroll
    for (int r = 0; r < 4; ++r) {
      float inv = 1.0f / l_i[mb][r];
      int qrow = qt * 128 + w * 32 + mb * 16 + q4 * 4 + r;
      bf16* op = ob + (size_t)(b * L + qrow) * C + h * DH;
#pragma unroll
      for (int nb = 0; nb < 4; ++nb)
        op[nb * 16 + c16] = (bf16)(o_acc[mb][nb][r] * inv);
    }
}

// ---------------- proj GEMM + bias + residual, output [B,C,L] fp32 ----------------
__global__ __launch_bounds__(256) void k_gemm_proj(const bf16* __restrict__ ob,
                                                   const bf16* __restrict__ wp,
                                                   const float* __restrict__ bp,
                                                   const float* __restrict__ x,
                                                   float* __restrict__ out) {
  int mt = blockIdx.x, nt = blockIdx.y;  // 128 x 8
  int m0 = mt << 6, n0 = nt << 6;
  int t = threadIdx.x;
  int lane = t & 63, w = t >> 6;
  int q4 = lane >> 4, c16 = lane & 15;
  __shared__ __align__(16) bf16 As[64][72];
  __shared__ __align__(16) bf16 Bs[64][72];
  __shared__ float Ot[64][65];
  f32x4 acc[4];
#pragma unroll
  for (int nb = 0; nb < 4; ++nb) acc[nb] = (f32x4){0.f, 0.f, 0.f, 0.f};

  for (int k0 = 0; k0 < C; k0 += 64) {
    __syncthreads();
#pragma unroll
    for (int p = 0; p < 2; ++p) {
      int idx = p * 256 + t;
      int row = idx >> 3, ch = idx & 7;
      *(bf16x8*)&As[row][ch * 8] = *(const bf16x8*)&ob[(size_t)(m0 + row) * C + k0 + ch * 8];
      *(bf16x8*)&Bs[row][ch * 8] = *(const bf16x8*)&wp[(size_t)(n0 + row) * C + k0 + ch * 8];
    }
    __syncthreads();
#pragma unroll
    for (int kk = 0; kk < 64; kk += 32) {
      bf16x8 a = ld8(&As[w * 16 + c16][kk + q4 * 8]);
#pragma unroll
      for (int nb = 0; nb < 4; ++nb) {
        bf16x8 bfr = ld8(&Bs[nb * 16 + c16][kk + q4 * 8]);
        acc[nb] = __builtin_amdgcn_mfma_f32_16x16x32_bf16(a, bfr, acc[nb], 0, 0, 0);
      }
    }
  }
  __syncthreads();
#pragma unroll
  for (int nb = 0; nb < 4; ++nb)
#pragma unroll
    for (int r = 0; r < 4; ++r)
      Ot[w * 16 + q4 * 4 + r][nb * 16 + c16] = acc[nb][r];
  __syncthreads();
  int b = m0 >> 11, l0 = m0 & (L - 1);
#pragma unroll
  for (int r = 0; r < 16; ++r) {
    int cl = w * 16 + r;
    int c = n0 + cl;
    size_t idx = (size_t)(b * C + c) * L + l0 + lane;
    out[idx] = Ot[lane][cl] + bp[c] + x[idx];
  }
}

extern "C" void kernel_launch(void* const* d_in, const int* in_sizes, int n_in,
                              void* d_out, int out_size, void* d_ws, size_t ws_size,
                              hipStream_t stream) {
  const float* x     = (const float*)d_in[0];
  const float* gamma = (const float*)d_in[1];
  const float* beta  = (const float*)d_in[2];
  const float* wqkv  = (const float*)d_in[3];
  const float* bqkv  = (const float*)d_in[4];
  const float* wproj = (const float*)d_in[5];
  const float* bproj = (const float*)d_in[6];
  float* out = (float*)d_out;
  char* ws = (char*)d_ws;
  bf16* hn  = (bf16*)(ws + OFF_HN);
  bf16* wqb = (bf16*)(ws + OFF_WQKV);
  bf16* wpb = (bf16*)(ws + OFF_WPROJ);
  bf16* qb  = (bf16*)(ws + OFF_Q);
  bf16* kb  = (bf16*)(ws + OFF_K);
  bf16* vb  = (bf16*)(ws + OFF_V);
  bf16* ob  = (bf16*)(ws + OFF_O);
  float* stats = (float*)(ws + OFF_STATS);

  hipLaunchKernelGGL(k_convert_w, dim3((N_QKV * C + 255) / 256), dim3(256), 0, stream,
                     wqkv, wproj, wqb, wpb);
  hipLaunchKernelGGL(k_ln_stats, dim3(B * (L / 64)), dim3(1024), 0, stream, x, stats);
  hipLaunchKernelGGL(k_ln_norm, dim3(B * (L / 64) * (C / 64)), dim3(256), 0, stream,
                     x, stats, gamma, beta, hn);
  hipLaunchKernelGGL(k_gemm_qkv, dim3(BL / 64, N_QKV / 64), dim3(256), 0, stream,
                     hn, wqb, bqkv, qb, kb, vb);
  hipLaunchKernelGGL(k_attn, dim3(B * H * (L / 128)), dim3(256), 0, stream, qb, kb, vb, ob);
  hipLaunchKernelGGL(k_gemm_proj, dim3(BL / 64, C / 64), dim3(256), 0, stream,
                     ob, wpb, bproj, x, out);
}